// Round 1
// baseline (2553.470 us; speedup 1.0000x reference)
//
#include <hip/hip_runtime.h>
#include <hip/hip_bf16.h>

#define BB 2048
#define DD 32
#define CC 128
#define HH 512
#define N1 1024   // 2*H
#define ROWS 16   // rows per block
#define NBLK (BB/ROWS)   // 128
#define THREADS 512

typedef float f32x4 __attribute__((ext_vector_type(4)));
typedef __bf16 bf16x8 __attribute__((ext_vector_type(8)));

// workspace layout (bytes): packed bf16 weight fragments, 1024B per 16x16x32 frag
#define W1A_OFF 0                         // 64 frags  (K=32 ->1 ktile, 64 ntiles)
#define W2_OFF  (64*1024)                 // 1024 frags (16 kt x 64 nt)
#define W3_OFF  (W2_OFF + 1024*1024)      // 32 frags   (16 kt x 2 nt)
#define W1C_OFF (W3_OFF + 32*1024)        // 256 frags  (4 kt x 64 nt)

static __device__ __forceinline__ __bf16 f2bf(float f) {
    __hip_bfloat16 h = __float2bfloat16(f);
    __bf16 r;
    __builtin_memcpy(&r, &h, 2);
    return r;
}

// Pack W [Kreal x N] fp32 row-major -> bf16 MFMA-B fragments.
// frag id = nt*KT + kt ; within frag: lane holds B[kt*32+(lane>>4)*8+j][nt*16+(lane&15)]
__global__ void pack_kernel(const float* __restrict__ W, __bf16* __restrict__ dst,
                            int Kreal, int N, int KT) {
    int frag = blockIdx.x;
    int lane = threadIdx.x;            // 64 threads
    int nt = frag / KT, kt = frag - nt * KT;
    int kbase = kt * 32 + (lane >> 4) * 8;
    int n = nt * 16 + (lane & 15);
    union { __bf16 b[8]; int4 v; } u;
#pragma unroll
    for (int j = 0; j < 8; j++) {
        int k = kbase + j;
        float v = (k < Kreal) ? W[(size_t)k * N + n] : 0.f;
        u.b[j] = f2bf(v);
    }
    *reinterpret_cast<int4*>(dst + (size_t)frag * 512 + lane * 8) = u.v;
}

__global__ __launch_bounds__(THREADS, 2)
void ccnf_main(const float* __restrict__ theta0,
               const float* __restrict__ ctx,
               const float* __restrict__ W1,
               const float* __restrict__ b1,
               const float* __restrict__ b2g,
               const float* __restrict__ b3g,
               const char* __restrict__ wsb,
               const int* __restrict__ nsteps_p,
               float* __restrict__ out)
{
    // LDS (total ~59 KB)
    __shared__ __bf16 cxt1[ROWS][1032];    // ctx@W1c + b1, bf16 (pad 1024->1032)
    __shared__ __bf16 hbuf[ROWS][520];     // shared h1/h2 buffer (pad 512->520)
    __shared__ __bf16 x_lds[ROWS * DD];    // theta-stage input tile [16][32]
    __shared__ __bf16 w1t_s[N1];           // W1 row 32 (time column)
    __shared__ __bf16 b2_s[N1];
    __shared__ float  b3_s[DD];
    __shared__ float  kpart[2 * ROWS * DD];

    const int tid  = threadIdx.x;
    const int lane = tid & 63;
    const int wv   = tid >> 6;             // 0..7
    const int row0 = blockIdx.x * ROWS;
    const int col  = lane & 15;            // C/D col
    const int rbase = (lane >> 4) * 4;     // C/D row base
    const int kgrp  = (lane >> 4) * 8;     // A-frag k base

    const bf16x8* w1a = reinterpret_cast<const bf16x8*>(wsb + W1A_OFF);
    const bf16x8* w2  = reinterpret_cast<const bf16x8*>(wsb + W2_OFF);
    const bf16x8* w3  = reinterpret_cast<const bf16x8*>(wsb + W3_OFF);
    const bf16x8* w1c = reinterpret_cast<const bf16x8*>(wsb + W1C_OFF);

    // ---- prologue: stage context (reuse hbuf), small vectors, theta ----
    __bf16* ctx_tmp = &hbuf[0][0];         // [16][136] bf16, stride 136
    for (int e = tid; e < ROWS * CC; e += THREADS) {
        int r = e >> 7, c = e & 127;
        ctx_tmp[r * 136 + c] = f2bf(ctx[(size_t)(row0 + r) * CC + c]);
    }
    for (int c = tid; c < N1; c += THREADS) {
        w1t_s[c] = f2bf(W1[32 * N1 + c]);
        b2_s[c]  = f2bf(b2g[c]);
    }
    if (tid < DD) b3_s[tid] = b3g[tid];
    float th_reg = theta0[row0 * DD + tid];     // thread owns element tid of [16][32]
    x_lds[tid] = f2bf(th_reg);
    const int nst = nsteps_p[0];
    const float dt = 1.0f / (float)nst;
    __syncthreads();

    // ---- cxt1 = ctx @ W1[33:161] + b1 (once) ----
    {
        bf16x8 caf[4];
#pragma unroll
        for (int kt = 0; kt < 4; kt++)
            caf[kt] = *reinterpret_cast<const bf16x8*>(&ctx_tmp[(lane & 15) * 136 + kt * 32 + kgrp]);
#pragma unroll
        for (int pi = 0; pi < 8; pi++) {
            int nt = wv * 8 + pi;
            f32x4 acc = {0.f, 0.f, 0.f, 0.f};
#pragma unroll
            for (int kt = 0; kt < 4; kt++)
                acc = __builtin_amdgcn_mfma_f32_16x16x32_bf16(caf[kt], w1c[(nt * 4 + kt) * 64 + lane], acc, 0, 0, 0);
#pragma unroll
            for (int i = 0; i < 4; i++)
                cxt1[rbase + i][nt * 16 + col] = f2bf(acc[i] + b1[nt * 16 + col]);
        }
    }
    __syncthreads();

    // ---- persistent RK4 loop ----
    float acck = 0.f;
    for (int step = 0; step < nst; ++step) {
        float tb = (float)step * dt;
        for (int s = 0; s < 4; ++s) {
            float tt = tb + ((s == 0) ? 0.f : (s == 3) ? dt : 0.5f * dt);

            // ---- Layer 1: theta-part (K=32) + cxt1 + t*w1t, GLU -> hbuf ----
            bf16x8 xf = *reinterpret_cast<const bf16x8*>(&x_lds[(lane & 15) * DD + kgrp]);
#pragma unroll
            for (int p = 0; p < 4; p++) {
                int a_nt = wv * 4 + p;
                int b_nt = a_nt + 32;
                f32x4 z = {0.f, 0.f, 0.f, 0.f};
                f32x4 aA = __builtin_amdgcn_mfma_f32_16x16x32_bf16(xf, w1a[a_nt * 64 + lane], z, 0, 0, 0);
                f32x4 aB = __builtin_amdgcn_mfma_f32_16x16x32_bf16(xf, w1a[b_nt * 64 + lane], z, 0, 0, 0);
                int ca = a_nt * 16 + col, cb = b_nt * 16 + col;
                float twa = tt * (float)w1t_s[ca];
                float twb = tt * (float)w1t_s[cb];
#pragma unroll
                for (int i = 0; i < 4; i++) {
                    int r = rbase + i;
                    float va = aA[i] + (float)cxt1[r][ca] + twa;
                    float vb = aB[i] + (float)cxt1[r][cb] + twb;
                    float hv = va * (1.f / (1.f + __expf(-vb)));
                    hbuf[r][a_nt * 16 + col] = f2bf(hv);
                }
            }
            __syncthreads();

            // ---- Layer 2: load full h1 into regs, then overwrite hbuf with h2 ----
            bf16x8 hA[16];
#pragma unroll
            for (int kt = 0; kt < 16; kt++)
                hA[kt] = *reinterpret_cast<const bf16x8*>(&hbuf[lane & 15][kt * 32 + kgrp]);
            __syncthreads();   // everyone done reading h1 before h2 overwrite
#pragma unroll
            for (int p = 0; p < 4; p++) {
                int a_nt = wv * 4 + p;
                int b_nt = a_nt + 32;
                f32x4 aA = {0.f, 0.f, 0.f, 0.f}, aB = {0.f, 0.f, 0.f, 0.f};
#pragma unroll
                for (int kt = 0; kt < 16; kt++) {
                    aA = __builtin_amdgcn_mfma_f32_16x16x32_bf16(hA[kt], w2[(a_nt * 16 + kt) * 64 + lane], aA, 0, 0, 0);
                    aB = __builtin_amdgcn_mfma_f32_16x16x32_bf16(hA[kt], w2[(b_nt * 16 + kt) * 64 + lane], aB, 0, 0, 0);
                }
                int ca = a_nt * 16 + col, cb = b_nt * 16 + col;
                float ba = (float)b2_s[ca], bb = (float)b2_s[cb];
#pragma unroll
                for (int i = 0; i < 4; i++) {
                    int r = rbase + i;
                    float va = aA[i] + ba;
                    float vb = aB[i] + bb;
                    float hv = va * (1.f / (1.f + __expf(-vb)));
                    hbuf[r][a_nt * 16 + col] = f2bf(hv);
                }
            }
            __syncthreads();

            // ---- Layer 3: k = h2 @ W3 + b3 (waves 0..3: 2 ntiles x 2 K-halves) ----
            if (wv < 4) {
                int nt = wv & 1, kh = wv >> 1;
                f32x4 acc = {0.f, 0.f, 0.f, 0.f};
#pragma unroll
                for (int kk = 0; kk < 8; kk++) {
                    int kt = kh * 8 + kk;
                    bf16x8 hf = *reinterpret_cast<const bf16x8*>(&hbuf[lane & 15][kt * 32 + kgrp]);
                    acc = __builtin_amdgcn_mfma_f32_16x16x32_bf16(hf, w3[(nt * 16 + kt) * 64 + lane], acc, 0, 0, 0);
                }
#pragma unroll
                for (int i = 0; i < 4; i++) {
                    int r = rbase + i;
                    float v = acc[i] + (kh == 0 ? b3_s[nt * 16 + col] : 0.f);
                    kpart[kh * 512 + r * DD + nt * 16 + col] = v;
                }
            }
            __syncthreads();

            // ---- RK4 combine (thread owns its element) ----
            float kv = kpart[tid] + kpart[512 + tid];
            float xe;
            if (s == 0)      { acck = kv;         xe = th_reg + 0.5f * dt * kv; }
            else if (s == 1) { acck += 2.f * kv;  xe = th_reg + 0.5f * dt * kv; }
            else if (s == 2) { acck += 2.f * kv;  xe = th_reg + dt * kv; }
            else             { th_reg += (dt / 6.f) * (acck + kv); xe = th_reg; }
            x_lds[tid] = f2bf(xe);
            __syncthreads();
        }
    }
    out[row0 * DD + tid] = th_reg;
}

extern "C" void kernel_launch(void* const* d_in, const int* in_sizes, int n_in,
                              void* d_out, int out_size, void* d_ws, size_t ws_size,
                              hipStream_t stream) {
    const float* theta0 = (const float*)d_in[0];
    const float* ctx    = (const float*)d_in[1];
    const float* W1     = (const float*)d_in[2];
    const float* b1     = (const float*)d_in[3];
    const float* W2     = (const float*)d_in[4];
    const float* b2     = (const float*)d_in[5];
    const float* W3     = (const float*)d_in[6];
    const float* b3     = (const float*)d_in[7];
    const int*   nst    = (const int*)d_in[8];
    float* out = (float*)d_out;
    char*  ws  = (char*)d_ws;

    __bf16* w1a = (__bf16*)(ws + W1A_OFF);
    __bf16* w2p = (__bf16*)(ws + W2_OFF);
    __bf16* w3p = (__bf16*)(ws + W3_OFF);
    __bf16* w1c = (__bf16*)(ws + W1C_OFF);

    // pack weights to MFMA fragment order (bf16)
    pack_kernel<<<64,   64, 0, stream>>>(W1,            w1a, 32,  N1, 1);
    pack_kernel<<<1024, 64, 0, stream>>>(W2,            w2p, 512, N1, 16);
    pack_kernel<<<32,   64, 0, stream>>>(W3,            w3p, 512, DD, 16);
    pack_kernel<<<256,  64, 0, stream>>>(W1 + 33 * N1,  w1c, CC,  N1, 4);

    ccnf_main<<<NBLK, THREADS, 0, stream>>>(theta0, ctx, W1, b1, b2, b3,
                                            (const char*)ws, nst, out);
}